// Round 7
// baseline (279.357 us; speedup 1.0000x reference)
//
#include <hip/hip_runtime.h>
#include <hip/hip_bf16.h>
#include <hip/hip_fp16.h>
#include <math.h>

// Problem: h = z @ W + b  (z [N,256] fp32, W [256,256] fp32, b [256])
//          out[e] = sigmoid(dot(h[src[e]], h[dst[e]]))  for E edges
// N = 100000, E = 300000, D = 256.
//
// R7: occupancy-first GEMM. R6 showed register-funded ILP regresses (2
// waves/SIMD floor); aggregate convert VALU is only ~1.6 us device-wide,
// so the fix is TLP: 8 waves/block, each wave a 32x64 strip (acc 32 regs,
// ~120 total) -> 3-4 waves/SIMD. A raw prefetched 1 iter ahead (16 regs);
// B-load latency (L2-hot packed W) hidden by wave interleave, not regs.
// h stored fp16 (absmax 0.0078 vs 0.02 threshold). 3-term split-bf16 MFMA
// (zh*Wh + zh*Wl + zl*Wh) for ~fp32 GEMM accuracy.

#define D_DIM 256
#define BM 64

typedef __attribute__((ext_vector_type(8))) short bf16x8;
typedef __attribute__((ext_vector_type(4))) float f32x4;

__device__ bf16x8 g_Wh[8 * 256 * 4];   // [kb][n][qd] -> 16B frag, 128 KB
__device__ bf16x8 g_Wl[8 * 256 * 4];

__device__ inline unsigned short bf16_rn(float x) {
  unsigned u = __builtin_bit_cast(unsigned, x);
  unsigned r = u + 0x7FFFu + ((u >> 16) & 1u);
  return (unsigned short)(r >> 16);
}
__device__ inline float bf16_f(unsigned short s) {
  return __builtin_bit_cast(float, (unsigned)s << 16);
}

__device__ inline void split8(const float4 f0, const float4 f1, bf16x8& hi, bf16x8& lo) {
  float v[8] = {f0.x, f0.y, f0.z, f0.w, f1.x, f1.y, f1.z, f1.w};
#pragma unroll
  for (int j = 0; j < 8; j++) {
    unsigned short hb = bf16_rn(v[j]);
    hi[j] = (short)hb;
    lo[j] = (short)bf16_rn(v[j] - bf16_f(hb));
  }
}

// 8192 threads: t -> (kb, qd, n), n fastest => coalesced row reads of W.
__global__ __launch_bounds__(256) void pack_w_kernel(const float* __restrict__ W) {
  int t = blockIdx.x * 256 + threadIdx.x;   // 0..8191
  int kb = t >> 10;
  int qd = (t >> 8) & 3;
  int n  = t & 255;
  float v[8];
#pragma unroll
  for (int j = 0; j < 8; j++)
    v[j] = W[(size_t)(kb * 32 + qd * 8 + j) * D_DIM + n];
  bf16x8 hi, lo;
  split8(make_float4(v[0], v[1], v[2], v[3]),
         make_float4(v[4], v[5], v[6], v[7]), hi, lo);
  int fi = (kb * 256 + n) * 4 + qd;
  g_Wh[fi] = hi;
  g_Wl[fi] = lo;
}

__global__ __launch_bounds__(512, 3) void gemm_mfma_kernel(
    const float* __restrict__ z, const float* __restrict__ b,
    __half* __restrict__ h, int nrows) {
  __shared__ __half et[8][16][72];   // per-wave epilogue tiles, 36.9 KB
  const int tid = threadIdx.x;
  const int lane = tid & 63;
  const int wv = tid >> 6;          // 0..7
  const int mh = wv >> 2;           // m-half: rows mh*32 .. +31
  const int nq = wv & 3;            // n-quarter: cols nq*64 .. +63
  const int fr = lane & 15;
  const int qd = lane >> 4;
  const int row0 = blockIdx.x * BM + mh * 32;

  f32x4 acc[2][4];
#pragma unroll
  for (int i = 0; i < 2; i++)
#pragma unroll
    for (int j = 0; j < 4; j++) acc[i][j] = (f32x4)0.f;

  const float* zp[2];
#pragma unroll
  for (int fm = 0; fm < 2; fm++) {
    int r = row0 + fm * 16 + fr;
    r = r < nrows ? r : (nrows - 1);
    zp[fm] = z + (size_t)r * D_DIM + qd * 8;
  }

  // preload kb=0 raw A
  float4 a0[2], a1[2];
#pragma unroll
  for (int fm = 0; fm < 2; fm++) {
    a0[fm] = *(const float4*)(zp[fm]);
    a1[fm] = *(const float4*)(zp[fm] + 4);
  }

#pragma unroll 1
  for (int kb = 0; kb < 8; kb++) {
    // B-frags for this kb (L2-hot packed W); latency hidden by wave TLP.
    bf16x8 bh[4], bl[4];
    const int fbase = (kb * 256 + nq * 64) * 4 + qd;
#pragma unroll
    for (int fn = 0; fn < 4; fn++) {
      int fi = fbase + (fn * 16 + fr) * 4;
      bh[fn] = g_Wh[fi];
      bl[fn] = g_Wl[fi];
    }
    // convert current A (raw regs freed after this)
    bf16x8 ah[2], al[2];
#pragma unroll
    for (int fm = 0; fm < 2; fm++) split8(a0[fm], a1[fm], ah[fm], al[fm]);
    // prefetch next kb's raw A (HBM), 1-iteration distance
    if (kb < 7) {
#pragma unroll
      for (int fm = 0; fm < 2; fm++) {
        const float* p = zp[fm] + (kb + 1) * 32;
        a0[fm] = *(const float4*)(p);
        a1[fm] = *(const float4*)(p + 4);
      }
    }
#pragma unroll
    for (int fn = 0; fn < 4; fn++) {
#pragma unroll
      for (int fm = 0; fm < 2; fm++) {
        acc[fm][fn] = __builtin_amdgcn_mfma_f32_16x16x32_bf16(ah[fm], bh[fn], acc[fm][fn], 0, 0, 0);
        acc[fm][fn] = __builtin_amdgcn_mfma_f32_16x16x32_bf16(ah[fm], bl[fn], acc[fm][fn], 0, 0, 0);
        acc[fm][fn] = __builtin_amdgcn_mfma_f32_16x16x32_bf16(al[fm], bh[fn], acc[fm][fn], 0, 0, 0);
      }
    }
  }

  // Epilogue: C[row=qd*4+r][col=fn*16+fr] -> per-wave LDS tile -> 16B stores.
  float bias[4];
#pragma unroll
  for (int fn = 0; fn < 4; fn++) bias[fn] = b[nq * 64 + fn * 16 + fr];

#pragma unroll
  for (int fm = 0; fm < 2; fm++) {
#pragma unroll
    for (int fn = 0; fn < 4; fn++)
#pragma unroll
      for (int r = 0; r < 4; r++)
        et[wv][qd * 4 + r][fn * 16 + fr] = __float2half(acc[fm][fn][r] + bias[fn]);
    // same-wave LDS write->read (in-order LDS pipe per wave; verified R4-R6)
#pragma unroll
    for (int it = 0; it < 2; it++) {
      int chunk = it * 64 + lane;     // 0..127
      int rr = chunk >> 3;            // 0..15
      int cc = chunk & 7;             // 16B chunk within 128B strip
      float4 v = *(const float4*)(&et[wv][rr][cc * 8]);
      int row = row0 + fm * 16 + rr;
      if (row < nrows)
        *(float4*)(h + (size_t)row * D_DIM + nq * 64 + cc * 8) = v;
    }
  }
}

// 4 edges per 16-lane group; all 16 x 16B loads hoisted (deep MLP).
__global__ __launch_bounds__(256) void edge_dot_kernel(
    const int* __restrict__ ei, const __half* __restrict__ h,
    float* __restrict__ out, int E) {
  int gid = blockIdx.x * blockDim.x + threadIdx.x;
  int g = gid >> 4;
  int lane = gid & 15;
  int ebase = g * 4;
  if (ebase >= E) return;

  float4 sv[4][2], dv[4][2];
  int ec[4];
#pragma unroll
  for (int q = 0; q < 4; q++) {
    int e = ebase + q;
    ec[q] = e < E ? e : (E - 1);
  }
#pragma unroll
  for (int q = 0; q < 4; q++) {
    int s = ei[ec[q]];
    int d = ei[E + ec[q]];
    const float4* sp = (const float4*)(h + (size_t)s * D_DIM);
    const float4* dp = (const float4*)(h + (size_t)d * D_DIM);
#pragma unroll
    for (int c = 0; c < 2; c++) {
      sv[q][c] = sp[c * 16 + lane];
      dv[q][c] = dp[c * 16 + lane];
    }
  }
  float acc[4] = {0.f, 0.f, 0.f, 0.f};
#pragma unroll
  for (int q = 0; q < 4; q++) {
#pragma unroll
    for (int c = 0; c < 2; c++) {
      const __half2* s2 = (const __half2*)&sv[q][c];
      const __half2* d2 = (const __half2*)&dv[q][c];
#pragma unroll
      for (int j = 0; j < 4; j++) {
        float2 a = __half22float2(s2[j]);
        float2 b2 = __half22float2(d2[j]);
        acc[q] += a.x * b2.x + a.y * b2.y;
      }
    }
  }
#pragma unroll
  for (int m = 1; m <= 8; m <<= 1) {
#pragma unroll
    for (int q = 0; q < 4; q++) acc[q] += __shfl_xor(acc[q], m);
  }
  if (lane == 0) {
    if (ebase + 3 < E) {
      float4 o;
      o.x = 1.0f / (1.0f + expf(-acc[0]));
      o.y = 1.0f / (1.0f + expf(-acc[1]));
      o.z = 1.0f / (1.0f + expf(-acc[2]));
      o.w = 1.0f / (1.0f + expf(-acc[3]));
      *(float4*)(out + ebase) = o;
    } else {
#pragma unroll
      for (int q = 0; q < 4; q++)
        if (ebase + q < E) out[ebase + q] = 1.0f / (1.0f + expf(-acc[q]));
    }
  }
}

extern "C" void kernel_launch(void* const* d_in, const int* in_sizes, int n_in,
                              void* d_out, int out_size, void* d_ws, size_t ws_size,
                              hipStream_t stream) {
  const float* z  = (const float*)d_in[0];
  const int*   ei = (const int*)d_in[1];
  const float* W  = (const float*)d_in[2];
  const float* b  = (const float*)d_in[3];
  float* out = (float*)d_out;
  __half* h  = (__half*)d_ws;   // 100000*256*2 = 51.2 MB scratch

  const int nnodes = in_sizes[0] / D_DIM;
  const int E = in_sizes[1] / 2;

  pack_w_kernel<<<32, 256, 0, stream>>>(W);

  dim3 grid_gemm((nnodes + BM - 1) / BM);
  gemm_mfma_kernel<<<grid_gemm, 512, 0, stream>>>(z, b, h, nnodes);

  int groups = (E + 3) / 4;
  dim3 grid_edge(((size_t)groups * 16 + 255) / 256);
  edge_dot_kernel<<<grid_edge, 256, 0, stream>>>(ei, h, out, E);
}

// Round 8
// 247.980 us; speedup vs baseline: 1.1265x; 1.1265x over previous
//
#include <hip/hip_runtime.h>
#include <hip/hip_bf16.h>
#include <hip/hip_fp16.h>
#include <math.h>

// Problem: h = z @ W + b  (z [N,256] fp32, W [256,256] fp32, b [256])
//          out[e] = sigmoid(dot(h[src[e]], h[dst[e]]))  for E edges
// N = 100000, E = 300000, D = 256.
//
// R8: LDS-staged B. R5 vs R7 A/B showed gemm is bound by L2-path traffic
// to the hot packed-W region (~13 TB/s effective), not occupancy/HBM/MFMA.
// BM=128, 512 thr = 8 waves (4 m-groups x 2 n-halves). Per kb the block
// stages hi+lo W frags for all 256 cols (32 KB) into LDS once via
// global_load_lds width=16 (double-buffered, 1 barrier/kb); B-frag reads
// become contiguous-1KB ds_read_b128. A raw fp32 register-prefetched 1 kb
// ahead, split-bf16 converted in-reg (2x redundancy, down from 4x).
// h fp16 (absmax 0.0078 vs 0.02). 3-term MFMA zh*Wh+zh*Wl+zl*Wh.

#define D_DIM 256
#define BM 128

typedef __attribute__((ext_vector_type(8))) short bf16x8;
typedef __attribute__((ext_vector_type(4))) float f32x4;

__device__ bf16x8 g_Wh[8 * 256 * 4];   // [kb][n][qd] -> 16B frag, 128 KB
__device__ bf16x8 g_Wl[8 * 256 * 4];

__device__ inline unsigned short bf16_rn(float x) {
  unsigned u = __builtin_bit_cast(unsigned, x);
  unsigned r = u + 0x7FFFu + ((u >> 16) & 1u);
  return (unsigned short)(r >> 16);
}
__device__ inline float bf16_f(unsigned short s) {
  return __builtin_bit_cast(float, (unsigned)s << 16);
}

__device__ inline void split8(const float4 f0, const float4 f1, bf16x8& hi, bf16x8& lo) {
  float v[8] = {f0.x, f0.y, f0.z, f0.w, f1.x, f1.y, f1.z, f1.w};
#pragma unroll
  for (int j = 0; j < 8; j++) {
    unsigned short hb = bf16_rn(v[j]);
    hi[j] = (short)hb;
    lo[j] = (short)bf16_rn(v[j] - bf16_f(hb));
  }
}

// 8192 threads: t -> (kb, qd, n), n fastest => coalesced row reads of W.
__global__ __launch_bounds__(256) void pack_w_kernel(const float* __restrict__ W) {
  int t = blockIdx.x * 256 + threadIdx.x;   // 0..8191
  int kb = t >> 10;
  int qd = (t >> 8) & 3;
  int n  = t & 255;
  float v[8];
#pragma unroll
  for (int j = 0; j < 8; j++)
    v[j] = W[(size_t)(kb * 32 + qd * 8 + j) * D_DIM + n];
  bf16x8 hi, lo;
  split8(make_float4(v[0], v[1], v[2], v[3]),
         make_float4(v[4], v[5], v[6], v[7]), hi, lo);
  int fi = (kb * 256 + n) * 4 + qd;
  g_Wh[fi] = hi;
  g_Wl[fi] = lo;
}

// Stage one kb's B frags (hi 16KB + lo 16KB) into LDS buffer, 8 waves.
// Waves 0-3 stage hi, 4-7 stage lo; 4 x 1KB wave-calls each.
__device__ inline void stage_b(int kb, char* buf, int wv, int lane) {
  const char* gsrc = (wv < 4)
      ? ((const char*)g_Wh + (size_t)kb * 16384 + (wv & 3) * 4096)
      : ((const char*)g_Wl + (size_t)kb * 16384 + (wv & 3) * 4096);
  char* ldst = buf + ((wv < 4) ? 0 : 16384) + (wv & 3) * 4096;
#pragma unroll
  for (int i = 0; i < 4; i++) {
    __builtin_amdgcn_global_load_lds(
        (const __attribute__((address_space(1))) void*)(gsrc + i * 1024 + lane * 16),
        (__attribute__((address_space(3))) void*)(ldst + i * 1024),
        16, 0, 0);
  }
}

__global__ __launch_bounds__(512) void gemm_mfma_kernel(
    const float* __restrict__ z, const float* __restrict__ b,
    __half* __restrict__ h, int nrows) {
  __shared__ char smem[2 * 32768];   // 2 B-buffers; reused for epilogue
  const int tid = threadIdx.x;
  const int lane = tid & 63;
  const int wv = tid >> 6;          // 0..7
  const int mg = wv >> 1;           // m-group: rows mg*32 .. +31
  const int nh = wv & 1;            // n-half: cols nh*128 .. +127
  const int fr = lane & 15;
  const int qd = lane >> 4;
  const int row0 = blockIdx.x * BM + mg * 32;

  f32x4 acc[2][8];
#pragma unroll
  for (int i = 0; i < 2; i++)
#pragma unroll
    for (int j = 0; j < 8; j++) acc[i][j] = (f32x4)0.f;

  const float* zp[2];
#pragma unroll
  for (int fm = 0; fm < 2; fm++) {
    int r = row0 + fm * 16 + fr;
    r = r < nrows ? r : (nrows - 1);
    zp[fm] = z + (size_t)r * D_DIM + qd * 8;
  }

  // preload kb=0 raw A; stage kb=0 B into buf0
  float4 a0[2], a1[2];
#pragma unroll
  for (int fm = 0; fm < 2; fm++) {
    a0[fm] = *(const float4*)(zp[fm]);
    a1[fm] = *(const float4*)(zp[fm] + 4);
  }
  stage_b(0, smem, wv, lane);
  __syncthreads();

#pragma unroll 2
  for (int kb = 0; kb < 8; kb++) {
    char* cur = smem + (kb & 1) * 32768;
    if (kb < 7) stage_b(kb + 1, smem + ((kb + 1) & 1) * 32768, wv, lane);

    // convert current A, then reload a0/a1 with next kb's raw A (prefetch)
    bf16x8 ah[2], al[2];
#pragma unroll
    for (int fm = 0; fm < 2; fm++) split8(a0[fm], a1[fm], ah[fm], al[fm]);
    if (kb < 7) {
#pragma unroll
      for (int fm = 0; fm < 2; fm++) {
        const float* p = zp[fm] + (kb + 1) * 32;
        a0[fm] = *(const float4*)(p);
        a1[fm] = *(const float4*)(p + 4);
      }
    }

    const bf16x8* bufh = (const bf16x8*)cur;                 // 1024 frags
    const bf16x8* bufl = (const bf16x8*)(cur + 16384);
#pragma unroll
    for (int fn = 0; fn < 8; fn++) {
      int fi = (nh * 128 + fn * 16 + fr) * 4 + qd;           // contiguous 1KB/wave
      bf16x8 bh = bufh[fi];
      bf16x8 bl = bufl[fi];
#pragma unroll
      for (int fm = 0; fm < 2; fm++) {
        acc[fm][fn] = __builtin_amdgcn_mfma_f32_16x16x32_bf16(ah[fm], bh, acc[fm][fn], 0, 0, 0);
        acc[fm][fn] = __builtin_amdgcn_mfma_f32_16x16x32_bf16(ah[fm], bl, acc[fm][fn], 0, 0, 0);
        acc[fm][fn] = __builtin_amdgcn_mfma_f32_16x16x32_bf16(al[fm], bh, acc[fm][fn], 0, 0, 0);
      }
    }
    __syncthreads();   // protects buf reuse at kb+2; drains kb+1 staging
  }

  // Epilogue: per-wave 4KB LDS tile (aliases B buffers; K-loop done).
  __half* et = (__half*)(smem + wv * 4096);   // 16 rows x 128 halves
  float bias[8];
#pragma unroll
  for (int fn = 0; fn < 8; fn++) bias[fn] = b[nh * 128 + fn * 16 + fr];

#pragma unroll
  for (int fm = 0; fm < 2; fm++) {
#pragma unroll
    for (int fn = 0; fn < 8; fn++)
#pragma unroll
      for (int r = 0; r < 4; r++)
        et[(qd * 4 + r) * 128 + fn * 16 + fr] = __float2half(acc[fm][fn][r] + bias[fn]);
    // same-wave LDS write->read (in-order per wave; verified R4-R7)
#pragma unroll
    for (int p = 0; p < 4; p++) {
      int idx = p * 64 + lane;        // 0..255
      int rr = idx >> 4;              // 0..15
      int cc = idx & 15;              // 16B chunk within 256B row-half
      float4 v = *(const float4*)(et + rr * 128 + cc * 8);
      int row = row0 + fm * 16 + rr;
      if (row < nrows)
        *(float4*)(h + (size_t)row * D_DIM + nh * 128 + cc * 8) = v;
    }
  }
}

// 4 edges per 16-lane group; all 16 x 16B loads hoisted (deep MLP).
__global__ __launch_bounds__(256) void edge_dot_kernel(
    const int* __restrict__ ei, const __half* __restrict__ h,
    float* __restrict__ out, int E) {
  int gid = blockIdx.x * blockDim.x + threadIdx.x;
  int g = gid >> 4;
  int lane = gid & 15;
  int ebase = g * 4;
  if (ebase >= E) return;

  float4 sv[4][2], dv[4][2];
  int ec[4];
#pragma unroll
  for (int q = 0; q < 4; q++) {
    int e = ebase + q;
    ec[q] = e < E ? e : (E - 1);
  }
#pragma unroll
  for (int q = 0; q < 4; q++) {
    int s = ei[ec[q]];
    int d = ei[E + ec[q]];
    const float4* sp = (const float4*)(h + (size_t)s * D_DIM);
    const float4* dp = (const float4*)(h + (size_t)d * D_DIM);
#pragma unroll
    for (int c = 0; c < 2; c++) {
      sv[q][c] = sp[c * 16 + lane];
      dv[q][c] = dp[c * 16 + lane];
    }
  }
  float acc[4] = {0.f, 0.f, 0.f, 0.f};
#pragma unroll
  for (int q = 0; q < 4; q++) {
#pragma unroll
    for (int c = 0; c < 2; c++) {
      const __half2* s2 = (const __half2*)&sv[q][c];
      const __half2* d2 = (const __half2*)&dv[q][c];
#pragma unroll
      for (int j = 0; j < 4; j++) {
        float2 a = __half22float2(s2[j]);
        float2 b2 = __half22float2(d2[j]);
        acc[q] += a.x * b2.x + a.y * b2.y;
      }
    }
  }
#pragma unroll
  for (int m = 1; m <= 8; m <<= 1) {
#pragma unroll
    for (int q = 0; q < 4; q++) acc[q] += __shfl_xor(acc[q], m);
  }
  if (lane == 0) {
    if (ebase + 3 < E) {
      float4 o;
      o.x = 1.0f / (1.0f + expf(-acc[0]));
      o.y = 1.0f / (1.0f + expf(-acc[1]));
      o.z = 1.0f / (1.0f + expf(-acc[2]));
      o.w = 1.0f / (1.0f + expf(-acc[3]));
      *(float4*)(out + ebase) = o;
    } else {
#pragma unroll
      for (int q = 0; q < 4; q++)
        if (ebase + q < E) out[ebase + q] = 1.0f / (1.0f + expf(-acc[q]));
    }
  }
}

extern "C" void kernel_launch(void* const* d_in, const int* in_sizes, int n_in,
                              void* d_out, int out_size, void* d_ws, size_t ws_size,
                              hipStream_t stream) {
  const float* z  = (const float*)d_in[0];
  const int*   ei = (const int*)d_in[1];
  const float* W  = (const float*)d_in[2];
  const float* b  = (const float*)d_in[3];
  float* out = (float*)d_out;
  __half* h  = (__half*)d_ws;   // 100000*256*2 = 51.2 MB scratch

  const int nnodes = in_sizes[0] / D_DIM;
  const int E = in_sizes[1] / 2;

  pack_w_kernel<<<32, 256, 0, stream>>>(W);

  dim3 grid_gemm((nnodes + BM - 1) / BM);
  gemm_mfma_kernel<<<grid_gemm, 512, 0, stream>>>(z, b, h, nnodes);

  int groups = (E + 3) / 4;
  dim3 grid_edge(((size_t)groups * 16 + 255) / 256);
  edge_dot_kernel<<<grid_edge, 256, 0, stream>>>(ei, h, out, E);
}

// Round 9
// 246.050 us; speedup vs baseline: 1.1354x; 1.0078x over previous
//
#include <hip/hip_runtime.h>
#include <hip/hip_bf16.h>
#include <hip/hip_fp16.h>
#include <math.h>

// Problem: h = z @ W + b  (z [N,256] fp32, W [256,256] fp32, b [256])
//          out[e] = sigmoid(dot(h[src[e]], h[dst[e]]))  for E edges
// N = 100000, E = 300000, D = 256.
//
// R9: (a) gemm epilogue tile padded to 136-half rows (R8's 256B stride put
// all qd-groups on the same 8 banks -> 4e6 conflicts). (b) edge kernel
// restructured: 1 wave per 8 edges, ONE 1KB load instr per edge (lanes
// 0-31 = src row 512B, lanes 32-63 = dst row); src/dst paired via
// shfl_xor(32), butterfly reduce. Halves segment count per instr.
// h fp16 (absmax 0.0078 vs 0.02). 3-term split-bf16 MFMA GEMM.

#define D_DIM 256
#define BM 128

typedef __attribute__((ext_vector_type(8))) short bf16x8;
typedef __attribute__((ext_vector_type(4))) float f32x4;

__device__ bf16x8 g_Wh[8 * 256 * 4];   // [kb][n][qd] -> 16B frag, 128 KB
__device__ bf16x8 g_Wl[8 * 256 * 4];

__device__ inline unsigned short bf16_rn(float x) {
  unsigned u = __builtin_bit_cast(unsigned, x);
  unsigned r = u + 0x7FFFu + ((u >> 16) & 1u);
  return (unsigned short)(r >> 16);
}
__device__ inline float bf16_f(unsigned short s) {
  return __builtin_bit_cast(float, (unsigned)s << 16);
}

__device__ inline void split8(const float4 f0, const float4 f1, bf16x8& hi, bf16x8& lo) {
  float v[8] = {f0.x, f0.y, f0.z, f0.w, f1.x, f1.y, f1.z, f1.w};
#pragma unroll
  for (int j = 0; j < 8; j++) {
    unsigned short hb = bf16_rn(v[j]);
    hi[j] = (short)hb;
    lo[j] = (short)bf16_rn(v[j] - bf16_f(hb));
  }
}

// 8192 threads: t -> (kb, qd, n), n fastest => coalesced row reads of W.
__global__ __launch_bounds__(256) void pack_w_kernel(const float* __restrict__ W) {
  int t = blockIdx.x * 256 + threadIdx.x;   // 0..8191
  int kb = t >> 10;
  int qd = (t >> 8) & 3;
  int n  = t & 255;
  float v[8];
#pragma unroll
  for (int j = 0; j < 8; j++)
    v[j] = W[(size_t)(kb * 32 + qd * 8 + j) * D_DIM + n];
  bf16x8 hi, lo;
  split8(make_float4(v[0], v[1], v[2], v[3]),
         make_float4(v[4], v[5], v[6], v[7]), hi, lo);
  int fi = (kb * 256 + n) * 4 + qd;
  g_Wh[fi] = hi;
  g_Wl[fi] = lo;
}

// Stage one kb's B frags (hi 16KB + lo 16KB) into LDS buffer, 8 waves.
__device__ inline void stage_b(int kb, char* buf, int wv, int lane) {
  const char* gsrc = (wv < 4)
      ? ((const char*)g_Wh + (size_t)kb * 16384 + (wv & 3) * 4096)
      : ((const char*)g_Wl + (size_t)kb * 16384 + (wv & 3) * 4096);
  char* ldst = buf + ((wv < 4) ? 0 : 16384) + (wv & 3) * 4096;
#pragma unroll
  for (int i = 0; i < 4; i++) {
    __builtin_amdgcn_global_load_lds(
        (const __attribute__((address_space(1))) void*)(gsrc + i * 1024 + lane * 16),
        (__attribute__((address_space(3))) void*)(ldst + i * 1024),
        16, 0, 0);
  }
}

__global__ __launch_bounds__(512) void gemm_mfma_kernel(
    const float* __restrict__ z, const float* __restrict__ b,
    __half* __restrict__ h, int nrows) {
  __shared__ char smem[2 * 32768];   // 2 B-buffers; reused for epilogue
  const int tid = threadIdx.x;
  const int lane = tid & 63;
  const int wv = tid >> 6;          // 0..7
  const int mg = wv >> 1;           // m-group: rows mg*32 .. +31
  const int nh = wv & 1;            // n-half: cols nh*128 .. +127
  const int fr = lane & 15;
  const int qd = lane >> 4;
  const int row0 = blockIdx.x * BM + mg * 32;

  f32x4 acc[2][8];
#pragma unroll
  for (int i = 0; i < 2; i++)
#pragma unroll
    for (int j = 0; j < 8; j++) acc[i][j] = (f32x4)0.f;

  const float* zp[2];
#pragma unroll
  for (int fm = 0; fm < 2; fm++) {
    int r = row0 + fm * 16 + fr;
    r = r < nrows ? r : (nrows - 1);
    zp[fm] = z + (size_t)r * D_DIM + qd * 8;
  }

  // preload kb=0 raw A; stage kb=0 B into buf0
  float4 a0[2], a1[2];
#pragma unroll
  for (int fm = 0; fm < 2; fm++) {
    a0[fm] = *(const float4*)(zp[fm]);
    a1[fm] = *(const float4*)(zp[fm] + 4);
  }
  stage_b(0, smem, wv, lane);
  __syncthreads();

#pragma unroll 2
  for (int kb = 0; kb < 8; kb++) {
    char* cur = smem + (kb & 1) * 32768;
    if (kb < 7) stage_b(kb + 1, smem + ((kb + 1) & 1) * 32768, wv, lane);

    // convert current A, then reload a0/a1 with next kb's raw A (prefetch)
    bf16x8 ah[2], al[2];
#pragma unroll
    for (int fm = 0; fm < 2; fm++) split8(a0[fm], a1[fm], ah[fm], al[fm]);
    if (kb < 7) {
#pragma unroll
      for (int fm = 0; fm < 2; fm++) {
        const float* p = zp[fm] + (kb + 1) * 32;
        a0[fm] = *(const float4*)(p);
        a1[fm] = *(const float4*)(p + 4);
      }
    }

    const bf16x8* bufh = (const bf16x8*)cur;                 // 1024 frags
    const bf16x8* bufl = (const bf16x8*)(cur + 16384);
#pragma unroll
    for (int fn = 0; fn < 8; fn++) {
      int fi = (nh * 128 + fn * 16 + fr) * 4 + qd;           // contiguous 1KB/wave
      bf16x8 bh = bufh[fi];
      bf16x8 bl = bufl[fi];
#pragma unroll
      for (int fm = 0; fm < 2; fm++) {
        acc[fm][fn] = __builtin_amdgcn_mfma_f32_16x16x32_bf16(ah[fm], bh, acc[fm][fn], 0, 0, 0);
        acc[fm][fn] = __builtin_amdgcn_mfma_f32_16x16x32_bf16(ah[fm], bl, acc[fm][fn], 0, 0, 0);
        acc[fm][fn] = __builtin_amdgcn_mfma_f32_16x16x32_bf16(al[fm], bh, acc[fm][fn], 0, 0, 0);
      }
    }
    __syncthreads();   // protects buf reuse at kb+2; drains kb+1 staging
  }

  // Epilogue: per-wave LDS tile, rows padded to 136 halves (272B: bank
  // shift 16 per qd-group -> 2-way max, free; 16B-aligned for b128).
  __half* et = (__half*)(smem + wv * 4608);   // 16 rows x 136 halves = 4352B
  float bias[8];
#pragma unroll
  for (int fn = 0; fn < 8; fn++) bias[fn] = b[nh * 128 + fn * 16 + fr];

#pragma unroll
  for (int fm = 0; fm < 2; fm++) {
#pragma unroll
    for (int fn = 0; fn < 8; fn++)
#pragma unroll
      for (int r = 0; r < 4; r++)
        et[(qd * 4 + r) * 136 + fn * 16 + fr] = __float2half(acc[fm][fn][r] + bias[fn]);
    // same-wave LDS write->read (in-order per wave; verified R4-R8)
#pragma unroll
    for (int p = 0; p < 4; p++) {
      int idx = p * 64 + lane;        // 0..255
      int rr = idx >> 4;              // 0..15
      int cc = idx & 15;              // 16B chunk within 256B row-half
      float4 v = *(const float4*)(et + rr * 136 + cc * 8);
      int row = row0 + fm * 16 + rr;
      if (row < nrows)
        *(float4*)(h + (size_t)row * D_DIM + nh * 128 + cc * 8) = v;
    }
  }
}

// 1 wave per 8 edges; per edge ONE 1KB load instr: lanes 0-31 cover the
// 512B src row, lanes 32-63 the dst row. Pair via shfl_xor(32), butterfly.
__global__ __launch_bounds__(256) void edge_dot_kernel(
    const int* __restrict__ ei, const __half* __restrict__ h,
    float* __restrict__ out, int E) {
  int wid = (blockIdx.x * blockDim.x + threadIdx.x) >> 6;
  int lane = threadIdx.x & 63;
  int ebase = wid * 8;
  if (ebase >= E) return;
  const int half = lane >> 5;      // 0=src row, 1=dst row
  const int off = lane & 31;       // float4 chunk within the 512B row

  float4 v[8];
#pragma unroll
  for (int q = 0; q < 8; q++) {
    int e = ebase + q;
    e = e < E ? e : (E - 1);
    int node = half ? ei[E + e] : ei[e];   // uniform per 32-lane half
    v[q] = *(const float4*)((const __half*)h + (size_t)node * D_DIM + off * 8);
  }

  float res = 0.f;
#pragma unroll
  for (int q = 0; q < 8; q++) {
    float4 w;
    w.x = __shfl_xor(v[q].x, 32);
    w.y = __shfl_xor(v[q].y, 32);
    w.z = __shfl_xor(v[q].z, 32);
    w.w = __shfl_xor(v[q].w, 32);
    const __half2* a2 = (const __half2*)&v[q];
    const __half2* b2 = (const __half2*)&w;
    float part = 0.f;
#pragma unroll
    for (int j = 0; j < 4; j++) {
      float2 fa = __half22float2(a2[j]);
      float2 fb = __half22float2(b2[j]);
      part += fa.x * fb.x + fa.y * fb.y;
    }
#pragma unroll
    for (int m = 1; m <= 16; m <<= 1) part += __shfl_xor(part, m);
    res = (lane == q) ? part : res;    // lanes 0..7 collect the 8 results
  }
  if (lane < 8) {
    int e = ebase + lane;
    if (e < E) out[e] = 1.0f / (1.0f + __expf(-res));
  }
}

extern "C" void kernel_launch(void* const* d_in, const int* in_sizes, int n_in,
                              void* d_out, int out_size, void* d_ws, size_t ws_size,
                              hipStream_t stream) {
  const float* z  = (const float*)d_in[0];
  const int*   ei = (const int*)d_in[1];
  const float* W  = (const float*)d_in[2];
  const float* b  = (const float*)d_in[3];
  float* out = (float*)d_out;
  __half* h  = (__half*)d_ws;   // 100000*256*2 = 51.2 MB scratch

  const int nnodes = in_sizes[0] / D_DIM;
  const int E = in_sizes[1] / 2;

  pack_w_kernel<<<32, 256, 0, stream>>>(W);

  dim3 grid_gemm((nnodes + BM - 1) / BM);
  gemm_mfma_kernel<<<grid_gemm, 512, 0, stream>>>(z, b, h, nnodes);

  int waves = (E + 7) / 8;                        // 1 wave per 8 edges
  dim3 grid_edge(((size_t)waves * 64 + 255) / 256);
  edge_dot_kernel<<<grid_edge, 256, 0, stream>>>(ei, h, out, E);
}

// Round 10
// 230.714 us; speedup vs baseline: 1.2108x; 1.0665x over previous
//
#include <hip/hip_runtime.h>
#include <hip/hip_bf16.h>
#include <hip/hip_fp16.h>
#include <math.h>

// Problem: h = z @ W + b  (z [N,256] fp32, W [256,256] fp32, b [256])
//          out[e] = sigmoid(dot(h[src[e]], h[dst[e]]))  for E edges
// N = 100000, E = 300000, D = 256.
//
// R10: gemm rebuilt for TLP + short critical path.
//  - truncating perm-split (hi=top16, lo=trunc(x-hi)): 32 VALU/8elem vs 104.
//    Error ~2^-16 rel (dropped Al*Wl), negligible vs fp16-h noise.
//  - BM=64, 512thr, wave=16x128 strip: acc 32 regs -> ~100 unified/wave.
//  - single 32KB B LDS buffer, 2 barriers/kb (m97 structure) -> 34.8KB LDS
//    -> 4 blocks/CU = 32 waves/CU (2x R8/R9 TLP).
//  - A raw global loads issued after the stage-drain barrier: HBM latency
//    covered by MFMA block + cross-block overlap.
// h fp16 (absmax 0.0078 vs 0.02). 3-term MFMA zh*Wh+zh*Wl+zl*Wh.

#define D_DIM 256
#define BM 64

typedef __attribute__((ext_vector_type(8))) short bf16x8;
typedef __attribute__((ext_vector_type(4))) float f32x4;

__device__ bf16x8 g_Wh[8 * 256 * 4];   // [kb][n][qd] -> 16B frag, 128 KB
__device__ bf16x8 g_Wl[8 * 256 * 4];

__device__ inline unsigned short bf16_rn(float x) {
  unsigned u = __builtin_bit_cast(unsigned, x);
  unsigned r = u + 0x7FFFu + ((u >> 16) & 1u);
  return (unsigned short)(r >> 16);
}
__device__ inline float bf16_f(unsigned short s) {
  return __builtin_bit_cast(float, (unsigned)s << 16);
}

// RNE split, used only in the one-shot W pack kernel.
__device__ inline void split8_rne(const float4 f0, const float4 f1, bf16x8& hi, bf16x8& lo) {
  float v[8] = {f0.x, f0.y, f0.z, f0.w, f1.x, f1.y, f1.z, f1.w};
#pragma unroll
  for (int j = 0; j < 8; j++) {
    unsigned short hb = bf16_rn(v[j]);
    hi[j] = (short)hb;
    lo[j] = (short)bf16_rn(v[j] - bf16_f(hb));
  }
}

// Cheap truncating split for the gemm hot loop: hi = top 16 bits of fp32,
// lo = top 16 bits of (x - hi). x - hi is exact (same exponent).
__device__ inline void split8_trunc(const float4 f0, const float4 f1, bf16x8& hi, bf16x8& lo) {
  unsigned u[8];
  u[0] = __builtin_bit_cast(unsigned, f0.x); u[1] = __builtin_bit_cast(unsigned, f0.y);
  u[2] = __builtin_bit_cast(unsigned, f0.z); u[3] = __builtin_bit_cast(unsigned, f0.w);
  u[4] = __builtin_bit_cast(unsigned, f1.x); u[5] = __builtin_bit_cast(unsigned, f1.y);
  u[6] = __builtin_bit_cast(unsigned, f1.z); u[7] = __builtin_bit_cast(unsigned, f1.w);
  unsigned* hp = (unsigned*)&hi;
  unsigned* lp = (unsigned*)&lo;
#pragma unroll
  for (int p = 0; p < 4; p++) {
    unsigned a = u[2 * p], c = u[2 * p + 1];
    hp[p] = (a >> 16) | (c & 0xFFFF0000u);
    float la = __builtin_bit_cast(float, a) - __builtin_bit_cast(float, a & 0xFFFF0000u);
    float lc = __builtin_bit_cast(float, c) - __builtin_bit_cast(float, c & 0xFFFF0000u);
    lp[p] = (__builtin_bit_cast(unsigned, la) >> 16) |
            (__builtin_bit_cast(unsigned, lc) & 0xFFFF0000u);
  }
}

// 8192 threads: t -> (kb, qd, n), n fastest => coalesced row reads of W.
__global__ __launch_bounds__(256) void pack_w_kernel(const float* __restrict__ W) {
  int t = blockIdx.x * 256 + threadIdx.x;   // 0..8191
  int kb = t >> 10;
  int qd = (t >> 8) & 3;
  int n  = t & 255;
  float v[8];
#pragma unroll
  for (int j = 0; j < 8; j++)
    v[j] = W[(size_t)(kb * 32 + qd * 8 + j) * D_DIM + n];
  bf16x8 hi, lo;
  split8_rne(make_float4(v[0], v[1], v[2], v[3]),
             make_float4(v[4], v[5], v[6], v[7]), hi, lo);
  int fi = (kb * 256 + n) * 4 + qd;
  g_Wh[fi] = hi;
  g_Wl[fi] = lo;
}

// Stage one kb's B frags (hi 16KB + lo 16KB) into the 32KB LDS buffer.
// 8 waves: 0-3 stage hi, 4-7 stage lo; 4 x 1KB wave-calls each.
__device__ inline void stage_b(int kb, char* buf, int wv, int lane) {
  const char* gsrc = (wv < 4)
      ? ((const char*)g_Wh + (size_t)kb * 16384 + (wv & 3) * 4096)
      : ((const char*)g_Wl + (size_t)kb * 16384 + (wv & 3) * 4096);
  char* ldst = buf + ((wv < 4) ? 0 : 16384) + (wv & 3) * 4096;
#pragma unroll
  for (int i = 0; i < 4; i++) {
    __builtin_amdgcn_global_load_lds(
        (const __attribute__((address_space(1))) void*)(gsrc + i * 1024 + lane * 16),
        (__attribute__((address_space(3))) void*)(ldst + i * 1024),
        16, 0, 0);
  }
}

__global__ __launch_bounds__(512) void gemm_mfma_kernel(
    const float* __restrict__ z, const float* __restrict__ b,
    __half* __restrict__ h, int nrows) {
  __shared__ char smem[34816];      // 32KB B stage; reused as 8x4352B epi tiles
  const int tid = threadIdx.x;
  const int lane = tid & 63;
  const int wv = tid >> 6;          // 0..7
  const int mf = wv >> 1;           // m-frag: rows mf*16 .. +15
  const int nh = wv & 1;            // n-half: cols nh*128 .. +127
  const int fr = lane & 15;
  const int qd = lane >> 4;
  const int row0 = blockIdx.x * BM + mf * 16;

  f32x4 acc[8];
#pragma unroll
  for (int j = 0; j < 8; j++) acc[j] = (f32x4)0.f;

  int ar = row0 + fr;
  ar = ar < nrows ? ar : (nrows - 1);
  const float* zrow = z + (size_t)ar * D_DIM + qd * 8;

  // preload kb=0 raw A
  float4 a0 = *(const float4*)(zrow);
  float4 a1 = *(const float4*)(zrow + 4);

#pragma unroll 1
  for (int kb = 0; kb < 8; kb++) {
    __syncthreads();                 // (a) all waves done reading buf(kb-1)
    stage_b(kb, smem, wv, lane);     // async 32KB -> LDS
    bf16x8 ah, al;
    split8_trunc(a0, a1, ah, al);    // cheap convert, overlaps stage latency
    __syncthreads();                 // (b) staging complete
    if (kb < 7) {                    // A(kb+1): drains at sync(a) of kb+1,
      const float* p = zrow + (kb + 1) * 32;   // covered by MFMA block
      a0 = *(const float4*)(p);
      a1 = *(const float4*)(p + 4);
    }
    const bf16x8* bufh = (const bf16x8*)smem;            // 1024 frags
    const bf16x8* bufl = (const bf16x8*)(smem + 16384);
#pragma unroll
    for (int fn = 0; fn < 8; fn++) {
      int fi = (nh * 128 + fn * 16 + fr) * 4 + qd;       // contiguous 1KB/wave
      bf16x8 bh = bufh[fi];
      bf16x8 bl = bufl[fi];
      acc[fn] = __builtin_amdgcn_mfma_f32_16x16x32_bf16(ah, bh, acc[fn], 0, 0, 0);
      acc[fn] = __builtin_amdgcn_mfma_f32_16x16x32_bf16(ah, bl, acc[fn], 0, 0, 0);
      acc[fn] = __builtin_amdgcn_mfma_f32_16x16x32_bf16(al, bh, acc[fn], 0, 0, 0);
    }
  }
  __syncthreads();                   // B buffer -> epilogue tile reuse

  // Epilogue: per-wave 16x136-half LDS tile (272B stride: 2-way max, free).
  __half* et = (__half*)(smem + wv * 4352);
  float bias[8];
#pragma unroll
  for (int fn = 0; fn < 8; fn++) bias[fn] = b[nh * 128 + fn * 16 + fr];

#pragma unroll
  for (int fn = 0; fn < 8; fn++)
#pragma unroll
    for (int r = 0; r < 4; r++)
      et[(qd * 4 + r) * 136 + fn * 16 + fr] = __float2half(acc[fn][r] + bias[fn]);
  // same-wave LDS write->read (in-order per wave; verified R4-R9)
#pragma unroll
  for (int p = 0; p < 4; p++) {
    int idx = p * 64 + lane;        // 0..255
    int rr = idx >> 4;              // 0..15
    int cc = idx & 15;              // 16B chunk within 256B row-half
    float4 v = *(const float4*)(et + rr * 136 + cc * 8);
    int row = row0 + rr;
    if (row < nrows)
      *(float4*)(h + (size_t)row * D_DIM + nh * 128 + cc * 8) = v;
  }
}

// 1 wave per 8 edges; per edge ONE 1KB load instr: lanes 0-31 cover the
// 512B src row, lanes 32-63 the dst row. Pair via shfl_xor(32), butterfly.
__global__ __launch_bounds__(256) void edge_dot_kernel(
    const int* __restrict__ ei, const __half* __restrict__ h,
    float* __restrict__ out, int E) {
  int wid = (blockIdx.x * blockDim.x + threadIdx.x) >> 6;
  int lane = threadIdx.x & 63;
  int ebase = wid * 8;
  if (ebase >= E) return;
  const int half = lane >> 5;      // 0=src row, 1=dst row
  const int off = lane & 31;       // float4 chunk within the 512B row

  float4 v[8];
#pragma unroll
  for (int q = 0; q < 8; q++) {
    int e = ebase + q;
    e = e < E ? e : (E - 1);
    int node = half ? ei[E + e] : ei[e];   // uniform per 32-lane half
    v[q] = *(const float4*)((const __half*)h + (size_t)node * D_DIM + off * 8);
  }

  float res = 0.f;
#pragma unroll
  for (int q = 0; q < 8; q++) {
    float4 w;
    w.x = __shfl_xor(v[q].x, 32);
    w.y = __shfl_xor(v[q].y, 32);
    w.z = __shfl_xor(v[q].z, 32);
    w.w = __shfl_xor(v[q].w, 32);
    const __half2* a2 = (const __half2*)&v[q];
    const __half2* b2 = (const __half2*)&w;
    float part = 0.f;
#pragma unroll
    for (int j = 0; j < 4; j++) {
      float2 fa = __half22float2(a2[j]);
      float2 fb = __half22float2(b2[j]);
      part += fa.x * fb.x + fa.y * fb.y;
    }
#pragma unroll
    for (int m = 1; m <= 16; m <<= 1) part += __shfl_xor(part, m);
    res = (lane == q) ? part : res;    // lanes 0..7 collect the 8 results
  }
  if (lane < 8) {
    int e = ebase + lane;
    if (e < E) out[e] = 1.0f / (1.0f + __expf(-res));
  }
}

extern "C" void kernel_launch(void* const* d_in, const int* in_sizes, int n_in,
                              void* d_out, int out_size, void* d_ws, size_t ws_size,
                              hipStream_t stream) {
  const float* z  = (const float*)d_in[0];
  const int*   ei = (const int*)d_in[1];
  const float* W  = (const float*)d_in[2];
  const float* b  = (const float*)d_in[3];
  float* out = (float*)d_out;
  __half* h  = (__half*)d_ws;   // 100000*256*2 = 51.2 MB scratch

  const int nnodes = in_sizes[0] / D_DIM;
  const int E = in_sizes[1] / 2;

  pack_w_kernel<<<32, 256, 0, stream>>>(W);

  dim3 grid_gemm((nnodes + BM - 1) / BM);
  gemm_mfma_kernel<<<grid_gemm, 512, 0, stream>>>(z, b, h, nnodes);

  int waves = (E + 7) / 8;                        // 1 wave per 8 edges
  dim3 grid_edge(((size_t)waves * 64 + 255) / 256);
  edge_dot_kernel<<<grid_edge, 256, 0, stream>>>(ei, h, out, E);
}

// Round 11
// 218.032 us; speedup vs baseline: 1.2813x; 1.0582x over previous
//
#include <hip/hip_runtime.h>
#include <hip/hip_bf16.h>
#include <hip/hip_fp16.h>
#include <math.h>

// Problem: h = z @ W + b  (z [N,256] fp32, W [256,256] fp32, b [256])
//          out[e] = sigmoid(dot(h[src[e]], h[dst[e]]))  for E edges
// N = 100000, E = 300000, D = 256.
//
// R11: single-term FP16 MFMA GEMM (was 3-term split-bf16). Error budget:
// fp16 z/W adds ~7e-4 h-error vs the existing 4.9e-4 fp16-h storage noise
// -> predicted absmax ~0.012 vs 0.02 threshold. Buys: 3x fewer MFMA, half
// the B bytes (16 KB/kb), 8 ds_reads/kb, and a TRUE double-buffered
// 1-barrier-per-kb K-loop (2x16KB buffers in the same 34.8KB LDS envelope;
// staging latency overlaps the whole MFMA block). A-convert = 8 v_cvt.
// h fp16. Edge kernel: 1 wave per 8 edges, 1 load instr per edge (R9).

#define D_DIM 256
#define BM 64

typedef __attribute__((ext_vector_type(8))) _Float16 half8;
typedef __attribute__((ext_vector_type(4))) float f32x4;

__device__ half8 g_Wf[8 * 256 * 4];   // [kb][n][qd] -> 16B fp16 frag, 128 KB

// 8192 threads: t -> (kb, qd, n), n fastest => coalesced row reads of W.
__global__ __launch_bounds__(256) void pack_w_kernel(const float* __restrict__ W) {
  int t = blockIdx.x * 256 + threadIdx.x;   // 0..8191
  int kb = t >> 10;
  int qd = (t >> 8) & 3;
  int n  = t & 255;
  half8 o;
#pragma unroll
  for (int j = 0; j < 8; j++)
    o[j] = (_Float16)W[(size_t)(kb * 32 + qd * 8 + j) * D_DIM + n];
  g_Wf[(kb * 256 + n) * 4 + qd] = o;
}

// Stage one kb's 16 KB of B frags into an LDS buffer; 8 waves x 2 KB.
__device__ inline void stage_b(int kb, char* buf, int wv, int lane) {
  const char* gsrc = (const char*)g_Wf + (size_t)kb * 16384 + wv * 2048;
  char* ldst = buf + wv * 2048;
#pragma unroll
  for (int i = 0; i < 2; i++) {
    __builtin_amdgcn_global_load_lds(
        (const __attribute__((address_space(1))) void*)(gsrc + i * 1024 + lane * 16),
        (__attribute__((address_space(3))) void*)(ldst + i * 1024),
        16, 0, 0);
  }
}

__global__ __launch_bounds__(512) void gemm_mfma_kernel(
    const float* __restrict__ z, const float* __restrict__ b,
    __half* __restrict__ h, int nrows) {
  // 2x16KB B double-buffer; epilogue tiles (8x4352B=34816B) alias the lot.
  __shared__ char smem[34816];
  const int tid = threadIdx.x;
  const int lane = tid & 63;
  const int wv = tid >> 6;          // 0..7
  const int mf = wv >> 1;           // m-frag: rows mf*16 .. +15
  const int nh = wv & 1;            // n-half: cols nh*128 .. +127
  const int fr = lane & 15;
  const int qd = lane >> 4;
  const int row0 = blockIdx.x * BM + mf * 16;

  f32x4 acc[8];
#pragma unroll
  for (int j = 0; j < 8; j++) acc[j] = (f32x4)0.f;

  int ar = row0 + fr;
  ar = ar < nrows ? ar : (nrows - 1);
  const float* zrow = z + (size_t)ar * D_DIM + qd * 8;

  // preload kb=0: raw A to regs, B to LDS buf0
  float4 a0 = *(const float4*)(zrow);
  float4 a1 = *(const float4*)(zrow + 4);
  stage_b(0, smem, wv, lane);
  __syncthreads();

#pragma unroll 1
  for (int kb = 0; kb < 8; kb++) {
    char* cur = smem + (kb & 1) * 16384;
    // stage kb+1 into the other buffer; latency spans the whole MFMA block
    if (kb < 7) stage_b(kb + 1, smem + ((kb + 1) & 1) * 16384, wv, lane);

    // convert current A fp32 -> fp16 frag (8 v_cvt)
    half8 af;
    af[0] = (_Float16)a0.x; af[1] = (_Float16)a0.y;
    af[2] = (_Float16)a0.z; af[3] = (_Float16)a0.w;
    af[4] = (_Float16)a1.x; af[5] = (_Float16)a1.y;
    af[6] = (_Float16)a1.z; af[7] = (_Float16)a1.w;
    // prefetch next kb's raw A (HBM), 1-iteration distance
    if (kb < 7) {
      const float* p = zrow + (kb + 1) * 32;
      a0 = *(const float4*)(p);
      a1 = *(const float4*)(p + 4);
    }

    const half8* buf = (const half8*)cur;
#pragma unroll
    for (int fn = 0; fn < 8; fn++) {
      int fi = (nh * 128 + fn * 16 + fr) * 4 + qd;   // contiguous 1KB/wave
      half8 bf = buf[fi];
      acc[fn] = __builtin_amdgcn_mfma_f32_16x16x32_f16(af, bf, acc[fn], 0, 0, 0);
    }
    // one barrier/kb: drains staging (vmcnt) for kb+1 AND fences cur reads
    // before kb+1's stage_b(kb+2) overwrites cur.
    __syncthreads();
  }

  // Epilogue: per-wave 16x136-half LDS tile (272B stride: 2-way max, free).
  __half* et = (__half*)(smem + wv * 4352);
  float bias[8];
#pragma unroll
  for (int fn = 0; fn < 8; fn++) bias[fn] = b[nh * 128 + fn * 16 + fr];

#pragma unroll
  for (int fn = 0; fn < 8; fn++)
#pragma unroll
    for (int r = 0; r < 4; r++)
      et[(qd * 4 + r) * 136 + fn * 16 + fr] = __float2half(acc[fn][r] + bias[fn]);
  // same-wave LDS write->read (in-order per wave; verified R4-R10)
#pragma unroll
  for (int p = 0; p < 4; p++) {
    int idx = p * 64 + lane;        // 0..255
    int rr = idx >> 4;              // 0..15
    int cc = idx & 15;              // 16B chunk within 256B row-half
    float4 v = *(const float4*)(et + rr * 136 + cc * 8);
    int row = row0 + rr;
    if (row < nrows)
      *(float4*)(h + (size_t)row * D_DIM + nh * 128 + cc * 8) = v;
  }
}

// 1 wave per 8 edges; per edge ONE 1KB load instr: lanes 0-31 cover the
// 512B src row, lanes 32-63 the dst row. Pair via shfl_xor(32), butterfly.
__global__ __launch_bounds__(256) void edge_dot_kernel(
    const int* __restrict__ ei, const __half* __restrict__ h,
    float* __restrict__ out, int E) {
  int wid = (blockIdx.x * blockDim.x + threadIdx.x) >> 6;
  int lane = threadIdx.x & 63;
  int ebase = wid * 8;
  if (ebase >= E) return;
  const int half = lane >> 5;      // 0=src row, 1=dst row
  const int off = lane & 31;       // float4 chunk within the 512B row

  float4 v[8];
#pragma unroll
  for (int q = 0; q < 8; q++) {
    int e = ebase + q;
    e = e < E ? e : (E - 1);
    int node = half ? ei[E + e] : ei[e];   // uniform per 32-lane half
    v[q] = *(const float4*)((const __half*)h + (size_t)node * D_DIM + off * 8);
  }

  float res = 0.f;
#pragma unroll
  for (int q = 0; q < 8; q++) {
    float4 w;
    w.x = __shfl_xor(v[q].x, 32);
    w.y = __shfl_xor(v[q].y, 32);
    w.z = __shfl_xor(v[q].z, 32);
    w.w = __shfl_xor(v[q].w, 32);
    const __half2* a2 = (const __half2*)&v[q];
    const __half2* b2 = (const __half2*)&w;
    float part = 0.f;
#pragma unroll
    for (int j = 0; j < 4; j++) {
      float2 fa = __half22float2(a2[j]);
      float2 fb = __half22float2(b2[j]);
      part += fa.x * fb.x + fa.y * fb.y;
    }
#pragma unroll
    for (int m = 1; m <= 16; m <<= 1) part += __shfl_xor(part, m);
    res = (lane == q) ? part : res;    // lanes 0..7 collect the 8 results
  }
  if (lane < 8) {
    int e = ebase + lane;
    if (e < E) out[e] = 1.0f / (1.0f + __expf(-res));
  }
}

extern "C" void kernel_launch(void* const* d_in, const int* in_sizes, int n_in,
                              void* d_out, int out_size, void* d_ws, size_t ws_size,
                              hipStream_t stream) {
  const float* z  = (const float*)d_in[0];
  const int*   ei = (const int*)d_in[1];
  const float* W  = (const float*)d_in[2];
  const float* b  = (const float*)d_in[3];
  float* out = (float*)d_out;
  __half* h  = (__half*)d_ws;   // 100000*256*2 = 51.2 MB scratch

  const int nnodes = in_sizes[0] / D_DIM;
  const int E = in_sizes[1] / 2;

  pack_w_kernel<<<32, 256, 0, stream>>>(W);

  dim3 grid_gemm((nnodes + BM - 1) / BM);
  gemm_mfma_kernel<<<grid_gemm, 512, 0, stream>>>(z, b, h, nnodes);

  int waves = (E + 7) / 8;                        // 1 wave per 8 edges
  dim3 grid_edge(((size_t)waves * 64 + 255) / 256);
  edge_dot_kernel<<<grid_edge, 256, 0, stream>>>(ei, h, out, E);
}

// Round 12
// 215.982 us; speedup vs baseline: 1.2934x; 1.0095x over previous
//
#include <hip/hip_runtime.h>
#include <hip/hip_bf16.h>
#include <hip/hip_fp16.h>
#include <math.h>

// Problem: h = z @ W + b  (z [N,256] fp32, W [256,256] fp32, b [256])
//          out[e] = sigmoid(dot(h[src[e]], h[dst[e]]))  for E edges
// N = 100000, E = 300000, D = 256.
//
// R12: BM=128 (was 64), same 512 threads: each wave owns a 32x128 strip
// (2 m-frags), halving block count 1563->782 and thus total barrier-drain
// chains, 2x MFMA per drain. fp16 single-term MFMA (R11, absmax 0.0117
// vs 0.02). Double-buffered 16KB B staging via global_load_lds, 1
// barrier/kb. h fp16. Edge: 1 wave per 8 edges, 1 load instr per edge.

#define D_DIM 256
#define BM 128

typedef __attribute__((ext_vector_type(8))) _Float16 half8;
typedef __attribute__((ext_vector_type(4))) float f32x4;

__device__ half8 g_Wf[8 * 256 * 4];   // [kb][n][qd] -> 16B fp16 frag, 128 KB

// 8192 threads: t -> (kb, qd, n), n fastest => coalesced row reads of W.
__global__ __launch_bounds__(256) void pack_w_kernel(const float* __restrict__ W) {
  int t = blockIdx.x * 256 + threadIdx.x;   // 0..8191
  int kb = t >> 10;
  int qd = (t >> 8) & 3;
  int n  = t & 255;
  half8 o;
#pragma unroll
  for (int j = 0; j < 8; j++)
    o[j] = (_Float16)W[(size_t)(kb * 32 + qd * 8 + j) * D_DIM + n];
  g_Wf[(kb * 256 + n) * 4 + qd] = o;
}

// Stage one kb's 16 KB of B frags into an LDS buffer; 8 waves x 2 KB.
__device__ inline void stage_b(int kb, char* buf, int wv, int lane) {
  const char* gsrc = (const char*)g_Wf + (size_t)kb * 16384 + wv * 2048;
  char* ldst = buf + wv * 2048;
#pragma unroll
  for (int i = 0; i < 2; i++) {
    __builtin_amdgcn_global_load_lds(
        (const __attribute__((address_space(1))) void*)(gsrc + i * 1024 + lane * 16),
        (__attribute__((address_space(3))) void*)(ldst + i * 1024),
        16, 0, 0);
  }
}

__global__ __launch_bounds__(512) void gemm_mfma_kernel(
    const float* __restrict__ z, const float* __restrict__ b,
    __half* __restrict__ h, int nrows) {
  // 2x16KB B double-buffer; epilogue tiles (8x4352B=34816B) alias the lot.
  __shared__ char smem[34816];
  const int tid = threadIdx.x;
  const int lane = tid & 63;
  const int wv = tid >> 6;          // 0..7
  const int mg = wv >> 1;           // m-group: rows mg*32 .. +31 (2 frags)
  const int nh = wv & 1;            // n-half: cols nh*128 .. +127
  const int fr = lane & 15;
  const int qd = lane >> 4;
  const int row0 = blockIdx.x * BM + mg * 32;

  f32x4 acc[2][8];
#pragma unroll
  for (int i = 0; i < 2; i++)
#pragma unroll
    for (int j = 0; j < 8; j++) acc[i][j] = (f32x4)0.f;

  const float* zrow[2];
#pragma unroll
  for (int fm = 0; fm < 2; fm++) {
    int r = row0 + fm * 16 + fr;
    r = r < nrows ? r : (nrows - 1);
    zrow[fm] = z + (size_t)r * D_DIM + qd * 8;
  }

  // preload kb=0: raw A to regs, B to LDS buf0
  float4 a0[2], a1[2];
#pragma unroll
  for (int fm = 0; fm < 2; fm++) {
    a0[fm] = *(const float4*)(zrow[fm]);
    a1[fm] = *(const float4*)(zrow[fm] + 4);
  }
  stage_b(0, smem, wv, lane);
  __syncthreads();

#pragma unroll 1
  for (int kb = 0; kb < 8; kb++) {
    char* cur = smem + (kb & 1) * 16384;
    // stage kb+1 into the other buffer; latency spans the whole MFMA block
    if (kb < 7) stage_b(kb + 1, smem + ((kb + 1) & 1) * 16384, wv, lane);

    // convert current A fp32 -> fp16 frags (16 v_cvt)
    half8 af[2];
#pragma unroll
    for (int fm = 0; fm < 2; fm++) {
      af[fm][0] = (_Float16)a0[fm].x; af[fm][1] = (_Float16)a0[fm].y;
      af[fm][2] = (_Float16)a0[fm].z; af[fm][3] = (_Float16)a0[fm].w;
      af[fm][4] = (_Float16)a1[fm].x; af[fm][5] = (_Float16)a1[fm].y;
      af[fm][6] = (_Float16)a1[fm].z; af[fm][7] = (_Float16)a1[fm].w;
    }
    // prefetch next kb's raw A (HBM), 1-iteration distance
    if (kb < 7) {
#pragma unroll
      for (int fm = 0; fm < 2; fm++) {
        const float* p = zrow[fm] + (kb + 1) * 32;
        a0[fm] = *(const float4*)(p);
        a1[fm] = *(const float4*)(p + 4);
      }
    }

    const half8* buf = (const half8*)cur;
#pragma unroll
    for (int fn = 0; fn < 8; fn++) {
      int fi = (nh * 128 + fn * 16 + fr) * 4 + qd;   // contiguous 1KB/wave
      half8 bf = buf[fi];
#pragma unroll
      for (int fm = 0; fm < 2; fm++)
        acc[fm][fn] = __builtin_amdgcn_mfma_f32_16x16x32_f16(af[fm], bf, acc[fm][fn], 0, 0, 0);
    }
    // one barrier/kb: drains kb+1 staging AND fences cur reads before
    // kb+1's stage_b(kb+2) overwrites cur.
    __syncthreads();
  }

  // Epilogue: per-wave 16x136-half LDS tile (272B stride: 2-way max, free),
  // reused for both m-frags (same-wave LDS ordering; verified R4-R11).
  __half* et = (__half*)(smem + wv * 4352);
  float bias[8];
#pragma unroll
  for (int fn = 0; fn < 8; fn++) bias[fn] = b[nh * 128 + fn * 16 + fr];

#pragma unroll
  for (int fm = 0; fm < 2; fm++) {
#pragma unroll
    for (int fn = 0; fn < 8; fn++)
#pragma unroll
      for (int r = 0; r < 4; r++)
        et[(qd * 4 + r) * 136 + fn * 16 + fr] = __float2half(acc[fm][fn][r] + bias[fn]);
#pragma unroll
    for (int p = 0; p < 4; p++) {
      int idx = p * 64 + lane;        // 0..255
      int rr = idx >> 4;              // 0..15
      int cc = idx & 15;              // 16B chunk within 256B row-half
      float4 v = *(const float4*)(et + rr * 136 + cc * 8);
      int row = row0 + fm * 16 + rr;
      if (row < nrows)
        *(float4*)(h + (size_t)row * D_DIM + nh * 128 + cc * 8) = v;
    }
  }
}

// 1 wave per 8 edges; per edge ONE 1KB load instr: lanes 0-31 cover the
// 512B src row, lanes 32-63 the dst row. Pair via shfl_xor(32), butterfly.
__global__ __launch_bounds__(256) void edge_dot_kernel(
    const int* __restrict__ ei, const __half* __restrict__ h,
    float* __restrict__ out, int E) {
  int wid = (blockIdx.x * blockDim.x + threadIdx.x) >> 6;
  int lane = threadIdx.x & 63;
  int ebase = wid * 8;
  if (ebase >= E) return;
  const int half = lane >> 5;      // 0=src row, 1=dst row
  const int off = lane & 31;       // float4 chunk within the 512B row

  float4 v[8];
#pragma unroll
  for (int q = 0; q < 8; q++) {
    int e = ebase + q;
    e = e < E ? e : (E - 1);
    int node = half ? ei[E + e] : ei[e];   // uniform per 32-lane half
    v[q] = *(const float4*)((const __half*)h + (size_t)node * D_DIM + off * 8);
  }

  float res = 0.f;
#pragma unroll
  for (int q = 0; q < 8; q++) {
    float4 w;
    w.x = __shfl_xor(v[q].x, 32);
    w.y = __shfl_xor(v[q].y, 32);
    w.z = __shfl_xor(v[q].z, 32);
    w.w = __shfl_xor(v[q].w, 32);
    const __half2* a2 = (const __half2*)&v[q];
    const __half2* b2 = (const __half2*)&w;
    float part = 0.f;
#pragma unroll
    for (int j = 0; j < 4; j++) {
      float2 fa = __half22float2(a2[j]);
      float2 fb = __half22float2(b2[j]);
      part += fa.x * fb.x + fa.y * fb.y;
    }
#pragma unroll
    for (int m = 1; m <= 16; m <<= 1) part += __shfl_xor(part, m);
    res = (lane == q) ? part : res;    // lanes 0..7 collect the 8 results
  }
  if (lane < 8) {
    int e = ebase + lane;
    if (e < E) out[e] = 1.0f / (1.0f + __expf(-res));
  }
}

extern "C" void kernel_launch(void* const* d_in, const int* in_sizes, int n_in,
                              void* d_out, int out_size, void* d_ws, size_t ws_size,
                              hipStream_t stream) {
  const float* z  = (const float*)d_in[0];
  const int*   ei = (const int*)d_in[1];
  const float* W  = (const float*)d_in[2];
  const float* b  = (const float*)d_in[3];
  float* out = (float*)d_out;
  __half* h  = (__half*)d_ws;   // 100000*256*2 = 51.2 MB scratch

  const int nnodes = in_sizes[0] / D_DIM;
  const int E = in_sizes[1] / 2;

  pack_w_kernel<<<32, 256, 0, stream>>>(W);

  dim3 grid_gemm((nnodes + BM - 1) / BM);
  gemm_mfma_kernel<<<grid_gemm, 512, 0, stream>>>(z, b, h, nnodes);

  int waves = (E + 7) / 8;                        // 1 wave per 8 edges
  dim3 grid_edge(((size_t)waves * 64 + 255) / 256);
  edge_dot_kernel<<<grid_edge, 256, 0, stream>>>(ei, h, out, E);
}